// Round 2
// baseline (2209.342 us; speedup 1.0000x reference)
//
#include <hip/hip_runtime.h>
#include <hip/hip_bf16.h>
#include <cstddef>

// RSAGEConv: 2-layer hetero SAGE (mean agg), N=50000, R=3, E=600000, 128->256->128.
// ALL float tensors are fp32 (reference is jnp.float32); indices int32; output fp32.
// Stages:
//  1) deg[r][n] (atomic counts) -> invdeg = 1/max(deg,1)   (in place)
//  2) scatter1: agg[r][dst] += x[src]          (fp32 atomics, 128-dim)
//  3) scale_agg: agg *= invdeg                 (now holds means)
//  4) gemm1: h = relu([x|agg0|agg1|agg2] @ B1cat + b1sum)      K=512 -> 256
//  5) gemm2: [out | y0 y1 y2] = h @ [Wself2sum | Wneigh2_r]    K=256 -> 512
//     (uses mean(h)@W == segsum((h@W)[src])/deg -> aggregate in 128-dim out space)
//  6) scatter2: out[dst] += y[r][src] * invdeg[r][dst]

#define NN 50000
#define RR 3
#define EE 600000
#define DIN 128
#define DHID 256
#define DOUT 128

// ---------------- degree ----------------
__global__ void deg_kernel(const int* __restrict__ dst, float* __restrict__ deg) {
    int idx = blockIdx.x * 256 + threadIdx.x;
    if (idx >= RR * EE) return;
    int r = idx / EE;
    atomicAdd(&deg[r * NN + dst[idx]], 1.0f);
}

__global__ void invdeg_kernel(float* __restrict__ deg) {
    int idx = blockIdx.x * 256 + threadIdx.x;
    if (idx >= RR * NN) return;
    deg[idx] = 1.0f / fmaxf(deg[idx], 1.0f);
}

// ---------------- weight prep ----------------
// B1cat [512][256]: rows 0..127 = sum_r Wself1[r]; rows 128+128r.. = Wneigh1[r]
__global__ void build_B1(const float* __restrict__ Ws, const float* __restrict__ Wn,
                         float* __restrict__ B1) {
    int idx = blockIdx.x * 256 + threadIdx.x;
    if (idx >= 512 * 256) return;
    int k = idx >> 8, j = idx & 255;
    float v;
    if (k < 128) {
        v = Ws[(size_t)(0 * 128 + k) * 256 + j]
          + Ws[(size_t)(1 * 128 + k) * 256 + j]
          + Ws[(size_t)(2 * 128 + k) * 256 + j];
    } else {
        int q = k - 128; int r = q >> 7; int kk = q & 127;
        v = Wn[((size_t)r * 128 + kk) * 256 + j];
    }
    B1[idx] = v;
}

// B2cat [256][512]: cols 0..127 = sum_r Wself2[r]; cols 128+128r.. = Wneigh2[r]
__global__ void build_B2(const float* __restrict__ Ws, const float* __restrict__ Wn,
                         float* __restrict__ B2) {
    int idx = blockIdx.x * 256 + threadIdx.x;
    if (idx >= 256 * 512) return;
    int k = idx >> 9, j = idx & 511;
    float v;
    if (j < 128) {
        v = Ws[(size_t)(0 * 256 + k) * 128 + j]
          + Ws[(size_t)(1 * 256 + k) * 128 + j]
          + Ws[(size_t)(2 * 256 + k) * 128 + j];
    } else {
        int q = j - 128; int r = q >> 7; int jj = q & 127;
        v = Wn[((size_t)r * 256 + k) * 128 + jj];
    }
    B2[idx] = v;
}

__global__ void build_bias(const float* __restrict__ b1, const float* __restrict__ b2,
                           float* __restrict__ bias1, float* __restrict__ bias2) {
    int idx = blockIdx.x * 256 + threadIdx.x;
    if (idx < 256) {
        bias1[idx] = b1[idx] + b1[256 + idx] + b1[512 + idx];
    } else if (idx < 384) {
        int j = idx - 256;
        bias2[j] = b2[j] + b2[128 + j] + b2[256 + j];
    }
}

// ---------------- scatter (segment sums) ----------------
__global__ void scatter1(const float* __restrict__ x, const int* __restrict__ src,
                         const int* __restrict__ dst, float* __restrict__ agg) {
    int e = blockIdx.x * 2 + (threadIdx.x >> 7);
    int c = threadIdx.x & 127;
    if (e >= RR * EE) return;
    int r = e / EE;
    int s = src[e], d = dst[e];
    float v = x[(size_t)s * DIN + c];
    atomicAdd(&agg[((size_t)r * NN + d) * DIN + c], v);
}

__global__ void scale_agg(float* __restrict__ agg, const float* __restrict__ invdeg) {
    size_t idx = (size_t)blockIdx.x * 256 + threadIdx.x;
    if (idx >= (size_t)RR * NN * DIN) return;
    agg[idx] *= invdeg[idx >> 7];
}

// ---------------- GEMM 1: [N,512] x [512,256] -> h [N,256], relu+bias ----------------
__global__ __launch_bounds__(256) void gemm1(const float* __restrict__ x,
        const float* __restrict__ agg, const float* __restrict__ B1,
        const float* __restrict__ bias1, float* __restrict__ h) {
    __shared__ float As[32][68];   // transposed: As[k][m]
    __shared__ float Bs[32][68];
    int t = threadIdx.x;
    int row0 = blockIdx.x * 64;
    int col0 = blockIdx.y * 64;
    int tx = t & 15, ty = t >> 4;
    float acc[4][4] = {};
    int lk = t & 31, lr0 = t >> 5;
    int lc = t & 63, lkb0 = t >> 6;
    for (int kb = 0; kb < 512; kb += 32) {
        #pragma unroll
        for (int i = 0; i < 8; ++i) {
            int rr = lr0 + i * 8;
            int grow = row0 + rr;
            int gk = kb + lk;
            float v = 0.f;
            if (grow < NN) {
                if (gk < DIN) v = x[(size_t)grow * DIN + gk];
                else {
                    int q = gk - DIN; int rel = q >> 7; int kk = q & 127;
                    v = agg[((size_t)rel * NN + grow) * DIN + kk];
                }
            }
            As[lk][rr] = v;
        }
        #pragma unroll
        for (int i = 0; i < 8; ++i) {
            int k = lkb0 + i * 4;
            Bs[k][lc] = B1[(size_t)(kb + k) * DHID + col0 + lc];
        }
        __syncthreads();
        #pragma unroll
        for (int k = 0; k < 32; ++k) {
            float a[4], b[4];
            #pragma unroll
            for (int i = 0; i < 4; ++i) a[i] = As[k][ty * 4 + i];
            #pragma unroll
            for (int j = 0; j < 4; ++j) b[j] = Bs[k][tx * 4 + j];
            #pragma unroll
            for (int i = 0; i < 4; ++i)
                #pragma unroll
                for (int j = 0; j < 4; ++j)
                    acc[i][j] += a[i] * b[j];
        }
        __syncthreads();
    }
    #pragma unroll
    for (int i = 0; i < 4; ++i) {
        int r = row0 + ty * 4 + i;
        if (r >= NN) continue;
        #pragma unroll
        for (int j = 0; j < 4; ++j) {
            int c = col0 + tx * 4 + j;
            h[(size_t)r * DHID + c] = fmaxf(acc[i][j] + bias1[c], 0.f);
        }
    }
}

// ---------------- GEMM 2: h [N,256] x B2 [256,512] -> out [N,128] + y [3][N][128] ----------------
__global__ __launch_bounds__(256) void gemm2(const float* __restrict__ h,
        const float* __restrict__ B2, const float* __restrict__ bias2,
        float* __restrict__ out, float* __restrict__ y) {
    __shared__ float As[32][68];
    __shared__ float Bs[32][68];
    int t = threadIdx.x;
    int row0 = blockIdx.x * 64;
    int col0 = blockIdx.y * 64;   // gridDim.y = 8 -> cols 0..511
    int tx = t & 15, ty = t >> 4;
    float acc[4][4] = {};
    int lk = t & 31, lr0 = t >> 5;
    int lc = t & 63, lkb0 = t >> 6;
    for (int kb = 0; kb < 256; kb += 32) {
        #pragma unroll
        for (int i = 0; i < 8; ++i) {
            int rr = lr0 + i * 8;
            int grow = row0 + rr;
            int gk = kb + lk;
            float v = 0.f;
            if (grow < NN) v = h[(size_t)grow * DHID + gk];
            As[lk][rr] = v;
        }
        #pragma unroll
        for (int i = 0; i < 8; ++i) {
            int k = lkb0 + i * 4;
            Bs[k][lc] = B2[(size_t)(kb + k) * 512 + col0 + lc];
        }
        __syncthreads();
        #pragma unroll
        for (int k = 0; k < 32; ++k) {
            float a[4], b[4];
            #pragma unroll
            for (int i = 0; i < 4; ++i) a[i] = As[k][ty * 4 + i];
            #pragma unroll
            for (int j = 0; j < 4; ++j) b[j] = Bs[k][tx * 4 + j];
            #pragma unroll
            for (int i = 0; i < 4; ++i)
                #pragma unroll
                for (int j = 0; j < 4; ++j)
                    acc[i][j] += a[i] * b[j];
        }
        __syncthreads();
    }
    #pragma unroll
    for (int i = 0; i < 4; ++i) {
        int r = row0 + ty * 4 + i;
        if (r >= NN) continue;
        #pragma unroll
        for (int j = 0; j < 4; ++j) {
            int c = col0 + tx * 4 + j;
            if (c < 128) {
                out[(size_t)r * 128 + c] = acc[i][j] + bias2[c];
            } else {
                int q = c - 128; int rel = q >> 7; int cc = q & 127;
                y[((size_t)rel * NN + r) * 128 + cc] = acc[i][j];
            }
        }
    }
}

__global__ void scatter2(const float* __restrict__ y, const int* __restrict__ src,
                         const int* __restrict__ dst, const float* __restrict__ invdeg,
                         float* __restrict__ out) {
    int e = blockIdx.x * 2 + (threadIdx.x >> 7);
    int c = threadIdx.x & 127;
    if (e >= RR * EE) return;
    int r = e / EE;
    int s = src[e], d = dst[e];
    float v = y[((size_t)r * NN + s) * 128 + c] * invdeg[r * NN + d];
    atomicAdd(&out[(size_t)d * 128 + c], v);
}

// ---------------- launch ----------------
extern "C" void kernel_launch(void* const* d_in, const int* in_sizes, int n_in,
                              void* d_out, int out_size, void* d_ws, size_t ws_size,
                              hipStream_t stream) {
    const float* x       = (const float*)d_in[0];
    const int*   src     = (const int*)  d_in[1];
    const int*   dst     = (const int*)  d_in[2];
    const float* Wself1  = (const float*)d_in[3];
    const float* Wneigh1 = (const float*)d_in[4];
    const float* b1      = (const float*)d_in[5];
    const float* Wself2  = (const float*)d_in[6];
    const float* Wneigh2 = (const float*)d_in[7];
    const float* b2      = (const float*)d_in[8];
    float* out = (float*)d_out;

    char* ws = (char*)d_ws;
    // layout (bytes):
    //   deg/invdeg : [0,        600KB)
    //   bias1      : [0xA0000,  +1KB)   bias2: [0xA1000, +512B)
    //   B1cat      : [0x100000, +512KB)
    //   B2cat      : [0x180000, +512KB)
    //   agg fp32   : [0x200000, +76.8MB)   (reused as y fp32 [3][N][128] after gemm1)
    //   h fp32     : [0x4F00000,+51.2MB)   (ends ~130MB)
    float* deg   = (float*)(ws + 0);
    float* bias1 = (float*)(ws + 0x000A0000ull);
    float* bias2 = (float*)(ws + 0x000A1000ull);
    float* B1    = (float*)(ws + 0x00100000ull);
    float* B2    = (float*)(ws + 0x00180000ull);
    float* agg   = (float*)(ws + 0x00200000ull);
    float* y     = (float*)(ws + 0x00200000ull);   // overlays agg (dead after gemm1)
    float* h     = (float*)(ws + 0x04F00000ull);

    hipMemsetAsync(deg, 0, (size_t)RR * NN * sizeof(float), stream);
    hipMemsetAsync(agg, 0, (size_t)RR * NN * DIN * sizeof(float), stream);

    build_B1<<<512 * 256 / 256, 256, 0, stream>>>(Wself1, Wneigh1, B1);
    build_B2<<<256 * 512 / 256, 256, 0, stream>>>(Wself2, Wneigh2, B2);
    build_bias<<<2, 256, 0, stream>>>(b1, b2, bias1, bias2);

    deg_kernel<<<(RR * EE + 255) / 256, 256, 0, stream>>>(dst, deg);
    invdeg_kernel<<<(RR * NN + 255) / 256, 256, 0, stream>>>(deg);

    scatter1<<<RR * EE / 2, 256, 0, stream>>>(x, src, dst, agg);
    scale_agg<<<(RR * NN * DIN + 255) / 256, 256, 0, stream>>>(agg, deg);

    gemm1<<<dim3((NN + 63) / 64, 4), 256, 0, stream>>>(x, agg, B1, bias1, h);
    gemm2<<<dim3((NN + 63) / 64, 8), 256, 0, stream>>>(h, B2, bias2, out, y);

    scatter2<<<RR * EE / 2, 256, 0, stream>>>(y, src, dst, deg, out);
}

// Round 3
// 936.849 us; speedup vs baseline: 2.3583x; 2.3583x over previous
//
#include <hip/hip_runtime.h>
#include <hip/hip_bf16.h>
#include <cstddef>

// RSAGEConv: 2-layer hetero SAGE (mean agg), N=50000, R=3, E=600000, 128->256->128.
// fp32 inputs/outputs. CSR-based gather aggregation (no fp32 atomics).
// Stages:
//  1) hist[r][n] = indegree (int atomics)
//  2) rowptr = exclusive_scan(hist)   (3-kernel hierarchical scan)
//  3) fill: col[rowptr[rn] + cursor++] = src   (CSR column lists)
//  4) gather1: agg[rn] = mean of x[src] rows (bf16 out), one wave per (r,node)
//  5) gemm1: h = relu([x|agg0|agg1|agg2] @ B1cat + b1sum)      K=512 -> 256
//  6) gemm2: [out | y0 y1 y2] = h @ [Wself2sum | Wneigh2_r]    K=256 -> 512 (y bf16)
//  7) gather2: out[n] += sum_r mean of y[r][src] rows, one wave per node

#define NN 50000
#define RR 3
#define EE 600000
#define DIN 128
#define DHID 256
#define DOUT 128
#define NRN (RR * NN)      // 150000

typedef __hip_bfloat16 bf16;
typedef __hip_bfloat162 bf162;

// ---------------- histogram (indegree) ----------------
__global__ void hist_kernel(const int* __restrict__ dst, int* __restrict__ hist) {
    int idx = blockIdx.x * 256 + threadIdx.x;
    if (idx >= RR * EE) return;
    int r = idx / EE;
    atomicAdd(&hist[r * NN + dst[idx]], 1);
}

// ---------------- exclusive scan over NRN ints ----------------
// scan_blocks: 1024 elems/block (256 thr x 4), writes exclusive-within-block + block total
__global__ __launch_bounds__(256) void scan_blocks(const int* __restrict__ in,
        int* __restrict__ out, int* __restrict__ bsums, int n) {
    int t = threadIdx.x;
    int base = blockIdx.x * 1024 + t * 4;
    int v[4];
    #pragma unroll
    for (int i = 0; i < 4; ++i) v[i] = (base + i < n) ? in[base + i] : 0;
    int s = v[0] + v[1] + v[2] + v[3];
    int lane = t & 63, wid = t >> 6;
    int sc = s;
    #pragma unroll
    for (int d = 1; d < 64; d <<= 1) {
        int tt = __shfl_up(sc, d, 64);
        if (lane >= d) sc += tt;
    }
    __shared__ int wsum[4], woff[4];
    if (lane == 63) wsum[wid] = sc;
    __syncthreads();
    if (t == 0) {
        int a = 0;
        #pragma unroll
        for (int i = 0; i < 4; ++i) { woff[i] = a; a += wsum[i]; }
    }
    __syncthreads();
    int run = sc - s + woff[wid];   // exclusive offset within block
    #pragma unroll
    for (int i = 0; i < 4; ++i) {
        if (base + i < n) out[base + i] = run;
        run += v[i];
    }
    if (t == 255) bsums[blockIdx.x] = woff[3] + wsum[3];
}

// scan_sums: single block, exclusive scan of nb block sums (nb <= 256)
__global__ __launch_bounds__(256) void scan_sums(int* __restrict__ bsums, int nb) {
    int t = threadIdx.x;
    int v = (t < nb) ? bsums[t] : 0;
    int lane = t & 63, wid = t >> 6;
    int sc = v;
    #pragma unroll
    for (int d = 1; d < 64; d <<= 1) {
        int tt = __shfl_up(sc, d, 64);
        if (lane >= d) sc += tt;
    }
    __shared__ int wsum[4], woff[4];
    if (lane == 63) wsum[wid] = sc;
    __syncthreads();
    if (t == 0) {
        int a = 0;
        #pragma unroll
        for (int i = 0; i < 4; ++i) { woff[i] = a; a += wsum[i]; }
    }
    __syncthreads();
    if (t < nb) bsums[t] = sc - v + woff[wid];
}

__global__ void add_offsets(int* __restrict__ rowptr, const int* __restrict__ bsums, int n) {
    int i = blockIdx.x * 256 + threadIdx.x;
    if (i < n) rowptr[i] += bsums[i >> 10];
    if (i == 0) rowptr[n] = RR * EE;
}

// ---------------- CSR fill ----------------
__global__ void fill_kernel(const int* __restrict__ src, const int* __restrict__ dst,
                            const int* __restrict__ rowptr, int* __restrict__ cursor,
                            int* __restrict__ col) {
    int idx = blockIdx.x * 256 + threadIdx.x;
    if (idx >= RR * EE) return;
    int r = idx / EE;
    int node = r * NN + dst[idx];
    int pos = rowptr[node] + atomicAdd(&cursor[node], 1);
    col[pos] = src[idx];
}

// ---------------- weight prep ----------------
__global__ void build_B1(const float* __restrict__ Ws, const float* __restrict__ Wn,
                         float* __restrict__ B1) {
    int idx = blockIdx.x * 256 + threadIdx.x;
    if (idx >= 512 * 256) return;
    int k = idx >> 8, j = idx & 255;
    float v;
    if (k < 128) {
        v = Ws[(size_t)k * 256 + j]
          + Ws[(size_t)(128 + k) * 256 + j]
          + Ws[(size_t)(256 + k) * 256 + j];
    } else {
        int q = k - 128; int r = q >> 7; int kk = q & 127;
        v = Wn[((size_t)r * 128 + kk) * 256 + j];
    }
    B1[idx] = v;
}

__global__ void build_B2(const float* __restrict__ Ws, const float* __restrict__ Wn,
                         float* __restrict__ B2) {
    int idx = blockIdx.x * 256 + threadIdx.x;
    if (idx >= 256 * 512) return;
    int k = idx >> 9, j = idx & 511;
    float v;
    if (j < 128) {
        v = Ws[(size_t)k * 128 + j]
          + Ws[(size_t)(256 + k) * 128 + j]
          + Ws[(size_t)(512 + k) * 128 + j];
    } else {
        int q = j - 128; int r = q >> 7; int jj = q & 127;
        v = Wn[((size_t)r * 256 + k) * 128 + jj];
    }
    B2[idx] = v;
}

__global__ void build_bias(const float* __restrict__ b1, const float* __restrict__ b2,
                           float* __restrict__ bias1, float* __restrict__ bias2) {
    int idx = blockIdx.x * 256 + threadIdx.x;
    if (idx < 256) {
        bias1[idx] = b1[idx] + b1[256 + idx] + b1[512 + idx];
    } else if (idx < 384) {
        int j = idx - 256;
        bias2[j] = b2[j] + b2[128 + j] + b2[256 + j];
    }
}

// ---------------- gather1: agg[g] = mean_{s in col[g]} x[s]  (bf16 out) ----------------
__global__ __launch_bounds__(256) void gather1(const float* __restrict__ x,
        const int* __restrict__ rowptr, const int* __restrict__ col,
        bf16* __restrict__ agg) {
    int g = blockIdx.x * 4 + (threadIdx.x >> 6);   // (r*NN + node), g < NRN
    int lane = threadIdx.x & 63;
    int beg = rowptr[g], end = rowptr[g + 1];
    float acc0 = 0.f, acc1 = 0.f;
    for (int base = beg; base < end; base += 64) {
        int cnt = min(64, end - base);
        int cidx = (lane < cnt) ? col[base + lane] : 0;
        for (int j = 0; j < cnt; ++j) {
            int s = __shfl(cidx, j, 64);
            float2 v = *(const float2*)&x[(size_t)s * DIN + lane * 2];
            acc0 += v.x; acc1 += v.y;
        }
    }
    float inv = 1.0f / fmaxf((float)(end - beg), 1.0f);
    bf162 o;
    o.x = __float2bfloat16(acc0 * inv);
    o.y = __float2bfloat16(acc1 * inv);
    *(bf162*)&agg[(size_t)g * DIN + lane * 2] = o;
}

// ---------------- GEMM 1: [N,512] x [512,256] -> h [N,256], relu+bias ----------------
__global__ __launch_bounds__(256) void gemm1(const float* __restrict__ x,
        const bf16* __restrict__ agg, const float* __restrict__ B1,
        const float* __restrict__ bias1, float* __restrict__ h) {
    __shared__ float As[32][68];   // transposed: As[k][m]
    __shared__ float Bs[32][68];
    int t = threadIdx.x;
    int row0 = blockIdx.x * 64;
    int col0 = blockIdx.y * 64;
    int tx = t & 15, ty = t >> 4;
    float acc[4][4] = {};
    int lk = t & 31, lr0 = t >> 5;
    int lc = t & 63, lkb0 = t >> 6;
    for (int kb = 0; kb < 512; kb += 32) {
        #pragma unroll
        for (int i = 0; i < 8; ++i) {
            int rr = lr0 + i * 8;
            int grow = row0 + rr;
            int gk = kb + lk;
            float v = 0.f;
            if (grow < NN) {
                if (gk < DIN) v = x[(size_t)grow * DIN + gk];
                else {
                    int q = gk - DIN; int rel = q >> 7; int kk = q & 127;
                    v = __bfloat162float(agg[((size_t)rel * NN + grow) * DIN + kk]);
                }
            }
            As[lk][rr] = v;
        }
        #pragma unroll
        for (int i = 0; i < 8; ++i) {
            int k = lkb0 + i * 4;
            Bs[k][lc] = B1[(size_t)(kb + k) * DHID + col0 + lc];
        }
        __syncthreads();
        #pragma unroll
        for (int k = 0; k < 32; ++k) {
            float a[4], b[4];
            #pragma unroll
            for (int i = 0; i < 4; ++i) a[i] = As[k][ty * 4 + i];
            #pragma unroll
            for (int j = 0; j < 4; ++j) b[j] = Bs[k][tx * 4 + j];
            #pragma unroll
            for (int i = 0; i < 4; ++i)
                #pragma unroll
                for (int j = 0; j < 4; ++j)
                    acc[i][j] += a[i] * b[j];
        }
        __syncthreads();
    }
    #pragma unroll
    for (int i = 0; i < 4; ++i) {
        int r = row0 + ty * 4 + i;
        if (r >= NN) continue;
        #pragma unroll
        for (int j = 0; j < 4; ++j) {
            int c = col0 + tx * 4 + j;
            h[(size_t)r * DHID + c] = fmaxf(acc[i][j] + bias1[c], 0.f);
        }
    }
}

// ---------------- GEMM 2: h [N,256] x B2 [256,512] -> out fp32 [N,128] + y bf16 [3][N][128] ----------------
__global__ __launch_bounds__(256) void gemm2(const float* __restrict__ h,
        const float* __restrict__ B2, const float* __restrict__ bias2,
        float* __restrict__ out, bf16* __restrict__ y) {
    __shared__ float As[32][68];
    __shared__ float Bs[32][68];
    int t = threadIdx.x;
    int row0 = blockIdx.x * 64;
    int col0 = blockIdx.y * 64;   // gridDim.y = 8 -> cols 0..511
    int tx = t & 15, ty = t >> 4;
    float acc[4][4] = {};
    int lk = t & 31, lr0 = t >> 5;
    int lc = t & 63, lkb0 = t >> 6;
    for (int kb = 0; kb < 256; kb += 32) {
        #pragma unroll
        for (int i = 0; i < 8; ++i) {
            int rr = lr0 + i * 8;
            int grow = row0 + rr;
            int gk = kb + lk;
            float v = 0.f;
            if (grow < NN) v = h[(size_t)grow * DHID + gk];
            As[lk][rr] = v;
        }
        #pragma unroll
        for (int i = 0; i < 8; ++i) {
            int k = lkb0 + i * 4;
            Bs[k][lc] = B2[(size_t)(kb + k) * 512 + col0 + lc];
        }
        __syncthreads();
        #pragma unroll
        for (int k = 0; k < 32; ++k) {
            float a[4], b[4];
            #pragma unroll
            for (int i = 0; i < 4; ++i) a[i] = As[k][ty * 4 + i];
            #pragma unroll
            for (int j = 0; j < 4; ++j) b[j] = Bs[k][tx * 4 + j];
            #pragma unroll
            for (int i = 0; i < 4; ++i)
                #pragma unroll
                for (int j = 0; j < 4; ++j)
                    acc[i][j] += a[i] * b[j];
        }
        __syncthreads();
    }
    #pragma unroll
    for (int i = 0; i < 4; ++i) {
        int r = row0 + ty * 4 + i;
        if (r >= NN) continue;
        #pragma unroll
        for (int j = 0; j < 4; ++j) {
            int c = col0 + tx * 4 + j;
            if (c < 128) {
                out[(size_t)r * 128 + c] = acc[i][j] + bias2[c];
            } else {
                int q = c - 128; int rel = q >> 7; int cc = q & 127;
                y[((size_t)rel * NN + r) * 128 + cc] = __float2bfloat16(acc[i][j]);
            }
        }
    }
}

// ---------------- gather2: out[n] += sum_r mean_{s in col[r,n]} y[r][s] ----------------
__global__ __launch_bounds__(256) void gather2(const bf16* __restrict__ y,
        const int* __restrict__ rowptr, const int* __restrict__ col,
        float* __restrict__ out) {
    int n = blockIdx.x * 4 + (threadIdx.x >> 6);   // node, n < NN
    int lane = threadIdx.x & 63;
    float2 acc = *(float2*)&out[(size_t)n * DOUT + lane * 2];  // self term + bias
    #pragma unroll
    for (int r = 0; r < RR; ++r) {
        int g = r * NN + n;
        int beg = rowptr[g], end = rowptr[g + 1];
        float a0 = 0.f, a1 = 0.f;
        for (int base = beg; base < end; base += 64) {
            int cnt = min(64, end - base);
            int cidx = (lane < cnt) ? col[base + lane] : 0;
            for (int j = 0; j < cnt; ++j) {
                int s = __shfl(cidx, j, 64);
                bf162 v = *(const bf162*)&y[((size_t)r * NN + s) * DOUT + lane * 2];
                a0 += __bfloat162float(v.x);
                a1 += __bfloat162float(v.y);
            }
        }
        float inv = 1.0f / fmaxf((float)(end - beg), 1.0f);
        acc.x += a0 * inv;
        acc.y += a1 * inv;
    }
    *(float2*)&out[(size_t)n * DOUT + lane * 2] = acc;
}

// ---------------- launch ----------------
extern "C" void kernel_launch(void* const* d_in, const int* in_sizes, int n_in,
                              void* d_out, int out_size, void* d_ws, size_t ws_size,
                              hipStream_t stream) {
    const float* x       = (const float*)d_in[0];
    const int*   src     = (const int*)  d_in[1];
    const int*   dst     = (const int*)  d_in[2];
    const float* Wself1  = (const float*)d_in[3];
    const float* Wneigh1 = (const float*)d_in[4];
    const float* b1      = (const float*)d_in[5];
    const float* Wself2  = (const float*)d_in[6];
    const float* Wneigh2 = (const float*)d_in[7];
    const float* b2      = (const float*)d_in[8];
    float* out = (float*)d_out;

    char* ws = (char*)d_ws;
    // layout (bytes):
    //   hist    : [0x0000000, 600,000)        int[150000]
    //   cursor  : [0x00A0000, 600,000)        int[150000]
    //   rowptr  : [0x0140000, 600,004)        int[150001]
    //   bsums   : [0x01E0000, 1KB)            int[<=256]
    //   bias1   : [0x01E1000, 1KB)  bias2: [0x01E2000, 512B)
    //   col     : [0x0200000, 7.2MB)          int[1800000]
    //   B1cat   : [0x0A00000, 512KB)
    //   B2cat   : [0x0A80000, 512KB)
    //   agg/y   : [0x0B00000, 38.4MB)         bf16[3][N][128] (agg dead after gemm1, y after)
    //   h       : [0x3100000, 51.2MB)         fp32[N][256]  (ends ~100MB)
    int*   hist   = (int*)  (ws + 0x0000000ull);
    int*   cursor = (int*)  (ws + 0x00A0000ull);
    int*   rowptr = (int*)  (ws + 0x0140000ull);
    int*   bsums  = (int*)  (ws + 0x01E0000ull);
    float* bias1  = (float*)(ws + 0x01E1000ull);
    float* bias2  = (float*)(ws + 0x01E2000ull);
    int*   col    = (int*)  (ws + 0x0200000ull);
    float* B1     = (float*)(ws + 0x0A00000ull);
    float* B2     = (float*)(ws + 0x0A80000ull);
    bf16*  agg    = (bf16*) (ws + 0x0B00000ull);
    bf16*  y      = (bf16*) (ws + 0x0B00000ull);   // overlays agg
    float* h      = (float*)(ws + 0x3100000ull);

    hipMemsetAsync(hist, 0, NRN * sizeof(int), stream);
    hipMemsetAsync(cursor, 0, NRN * sizeof(int), stream);

    build_B1<<<512 * 256 / 256, 256, 0, stream>>>(Wself1, Wneigh1, B1);
    build_B2<<<256 * 512 / 256, 256, 0, stream>>>(Wself2, Wneigh2, B2);
    build_bias<<<2, 256, 0, stream>>>(b1, b2, bias1, bias2);

    hist_kernel<<<(RR * EE + 255) / 256, 256, 0, stream>>>(dst, hist);

    const int nb = (NRN + 1023) / 1024;   // 147
    scan_blocks<<<nb, 256, 0, stream>>>(hist, rowptr, bsums, NRN);
    scan_sums<<<1, 256, 0, stream>>>(bsums, nb);
    add_offsets<<<(NRN + 255) / 256, 256, 0, stream>>>(rowptr, bsums, NRN);

    fill_kernel<<<(RR * EE + 255) / 256, 256, 0, stream>>>(src, dst, rowptr, cursor, col);

    gather1<<<NRN / 4, 256, 0, stream>>>(x, rowptr, col, agg);

    gemm1<<<dim3((NN + 63) / 64, 4), 256, 0, stream>>>(x, agg, B1, bias1, h);
    gemm2<<<dim3((NN + 63) / 64, 8), 256, 0, stream>>>(h, B2, bias2, out, y);

    gather2<<<NN / 4, 256, 0, stream>>>(y, rowptr, col, out);
}

// Round 4
// 602.850 us; speedup vs baseline: 3.6648x; 1.5540x over previous
//
#include <hip/hip_runtime.h>
#include <hip/hip_bf16.h>
#include <cstddef>

// RSAGEConv: 2-layer hetero SAGE (mean agg), N=50000, R=3, E=600000, 128->256->128.
// fp32 in/out. CSR gather aggregation + bf16 MFMA GEMMs.
// Pipeline:
//  hist -> scan -> fill (CSR)
//  convert_x: Abig[:,0:128] = bf16(x)
//  gather1:   Abig[:,128+128r] = mean_r(x)        (bf16, direct into Abig)
//  gemm1m:    h = bf16(relu(Abig @ B1t^T + bias1))   [MFMA, K=512 -> 256]
//  gemm2m:    out(fp32) | y(bf16) = h @ B2t^T + bias2 [MFMA, K=256 -> 512]
//  gather2:   out[n] += sum_r mean_r(y)

#define NN 50000
#define RR 3
#define EE 600000
#define DIN 128
#define DHID 256
#define DOUT 128
#define NRN (RR * NN)

typedef __hip_bfloat16 bf16;
typedef __hip_bfloat162 bf162;
typedef __attribute__((ext_vector_type(8))) short short8;
typedef __attribute__((ext_vector_type(4))) float floatx4;

__device__ __forceinline__ void async_copy16(const void* g, void* l) {
    __builtin_amdgcn_global_load_lds((const __attribute__((address_space(1))) void*)g,
                                     (__attribute__((address_space(3))) void*)l, 16, 0, 0);
}

// ---------------- histogram (indegree) ----------------
__global__ void hist_kernel(const int* __restrict__ dst, int* __restrict__ hist) {
    int idx = blockIdx.x * 256 + threadIdx.x;
    if (idx >= RR * EE) return;
    int r = idx / EE;
    atomicAdd(&hist[r * NN + dst[idx]], 1);
}

// ---------------- exclusive scan over NRN ints ----------------
__global__ __launch_bounds__(256) void scan_blocks(const int* __restrict__ in,
        int* __restrict__ out, int* __restrict__ bsums, int n) {
    int t = threadIdx.x;
    int base = blockIdx.x * 1024 + t * 4;
    int v[4];
    #pragma unroll
    for (int i = 0; i < 4; ++i) v[i] = (base + i < n) ? in[base + i] : 0;
    int s = v[0] + v[1] + v[2] + v[3];
    int lane = t & 63, wid = t >> 6;
    int sc = s;
    #pragma unroll
    for (int d = 1; d < 64; d <<= 1) {
        int tt = __shfl_up(sc, d, 64);
        if (lane >= d) sc += tt;
    }
    __shared__ int wsum[4], woff[4];
    if (lane == 63) wsum[wid] = sc;
    __syncthreads();
    if (t == 0) {
        int a = 0;
        #pragma unroll
        for (int i = 0; i < 4; ++i) { woff[i] = a; a += wsum[i]; }
    }
    __syncthreads();
    int run = sc - s + woff[wid];
    #pragma unroll
    for (int i = 0; i < 4; ++i) {
        if (base + i < n) out[base + i] = run;
        run += v[i];
    }
    if (t == 255) bsums[blockIdx.x] = woff[3] + wsum[3];
}

__global__ __launch_bounds__(256) void scan_sums(int* __restrict__ bsums, int nb) {
    int t = threadIdx.x;
    int v = (t < nb) ? bsums[t] : 0;
    int lane = t & 63, wid = t >> 6;
    int sc = v;
    #pragma unroll
    for (int d = 1; d < 64; d <<= 1) {
        int tt = __shfl_up(sc, d, 64);
        if (lane >= d) sc += tt;
    }
    __shared__ int wsum[4], woff[4];
    if (lane == 63) wsum[wid] = sc;
    __syncthreads();
    if (t == 0) {
        int a = 0;
        #pragma unroll
        for (int i = 0; i < 4; ++i) { woff[i] = a; a += wsum[i]; }
    }
    __syncthreads();
    if (t < nb) bsums[t] = sc - v + woff[wid];
}

__global__ void add_offsets(int* __restrict__ rowptr, const int* __restrict__ bsums, int n) {
    int i = blockIdx.x * 256 + threadIdx.x;
    if (i < n) rowptr[i] += bsums[i >> 10];
    if (i == 0) rowptr[n] = RR * EE;
}

// ---------------- CSR fill ----------------
__global__ void fill_kernel(const int* __restrict__ src, const int* __restrict__ dst,
                            const int* __restrict__ rowptr, int* __restrict__ cursor,
                            int* __restrict__ col) {
    int idx = blockIdx.x * 256 + threadIdx.x;
    if (idx >= RR * EE) return;
    int r = idx / EE;
    int node = r * NN + dst[idx];
    int pos = rowptr[node] + atomicAdd(&cursor[node], 1);
    col[pos] = src[idx];
}

// ---------------- weight prep (transposed, bf16) ----------------
// B1t [256][512]: B1t[n][k] = k<128 ? sum_r Wself1[r][k][n] : Wneigh1[(k-128)/128][k%128][n]
__global__ void build_B1t(const float* __restrict__ Ws, const float* __restrict__ Wn,
                          bf16* __restrict__ B1t) {
    int idx = blockIdx.x * 256 + threadIdx.x;
    if (idx >= 256 * 512) return;
    int n = idx >> 9, k = idx & 511;
    float v;
    if (k < 128) {
        v = Ws[(size_t)k * 256 + n]
          + Ws[(size_t)(128 + k) * 256 + n]
          + Ws[(size_t)(256 + k) * 256 + n];
    } else {
        int q = k - 128; int r = q >> 7; int kk = q & 127;
        v = Wn[((size_t)r * 128 + kk) * 256 + n];
    }
    B1t[(size_t)n * 512 + k] = __float2bfloat16(v);
}

// B2t [512][256]: B2t[n][k] = n<128 ? sum_r Wself2[r][k][n] : Wneigh2[(n-128)/128][k][n%128]
__global__ void build_B2t(const float* __restrict__ Ws, const float* __restrict__ Wn,
                          bf16* __restrict__ B2t) {
    int idx = blockIdx.x * 256 + threadIdx.x;
    if (idx >= 512 * 256) return;
    int n = idx >> 8, k = idx & 255;
    float v;
    if (n < 128) {
        v = Ws[(size_t)k * 128 + n]
          + Ws[(size_t)(256 + k) * 128 + n]
          + Ws[(size_t)(512 + k) * 128 + n];
    } else {
        int q = n - 128; int r = q >> 7; int nn = q & 127;
        v = Wn[((size_t)r * 256 + k) * 128 + nn];
    }
    B2t[(size_t)n * 256 + k] = __float2bfloat16(v);
}

__global__ void build_bias(const float* __restrict__ b1, const float* __restrict__ b2,
                           float* __restrict__ bias1, float* __restrict__ bias2) {
    int idx = blockIdx.x * 256 + threadIdx.x;
    if (idx < 256) {
        bias1[idx] = b1[idx] + b1[256 + idx] + b1[512 + idx];
    } else if (idx < 384) {
        int j = idx - 256;
        bias2[j] = b2[j] + b2[128 + j] + b2[256 + j];
    }
}

// ---------------- convert x -> Abig cols 0..127 ----------------
__global__ void convert_x(const float* __restrict__ x, bf16* __restrict__ Abig) {
    int idx = blockIdx.x * 256 + threadIdx.x;   // over N*64
    if (idx >= NN * 64) return;
    int n = idx >> 6, c2 = idx & 63;
    float2 v = *(const float2*)&x[(size_t)n * DIN + c2 * 2];
    bf162 o; o.x = __float2bfloat16(v.x); o.y = __float2bfloat16(v.y);
    *(bf162*)&Abig[(size_t)n * 512 + c2 * 2] = o;
}

// ---------------- gather1: Abig[n][128+128r..] = mean_{s in col[r,n]} x[s] ----------------
__global__ __launch_bounds__(256) void gather1(const float* __restrict__ x,
        const int* __restrict__ rowptr, const int* __restrict__ col,
        bf16* __restrict__ Abig) {
    int g = blockIdx.x * 4 + (threadIdx.x >> 6);   // r*NN + n
    int lane = threadIdx.x & 63;
    int r = g / NN;
    int n = g - r * NN;
    int beg = rowptr[g], end = rowptr[g + 1];
    float acc0 = 0.f, acc1 = 0.f;
    for (int base = beg; base < end; base += 64) {
        int cnt = min(64, end - base);
        int cidx = (lane < cnt) ? col[base + lane] : 0;
        for (int j = 0; j < cnt; ++j) {
            int s = __shfl(cidx, j, 64);
            float2 v = *(const float2*)&x[(size_t)s * DIN + lane * 2];
            acc0 += v.x; acc1 += v.y;
        }
    }
    float inv = 1.0f / fmaxf((float)(end - beg), 1.0f);
    bf162 o;
    o.x = __float2bfloat16(acc0 * inv);
    o.y = __float2bfloat16(acc1 * inv);
    *(bf162*)&Abig[(size_t)n * 512 + 128 + r * 128 + lane * 2] = o;
}

// ---------------- MFMA GEMM 1: Abig[N][512](bf16) x B1t[256][512] -> h bf16 [N][256] ----------------
// 256 thr = 4 waves (2x2), C tile 128x128, BK=32, mfma_f32_16x16x32_bf16.
__global__ __launch_bounds__(256) void gemm1m(const bf16* __restrict__ A,
        const bf16* __restrict__ Bt, const float* __restrict__ bias1,
        bf16* __restrict__ h) {
    __shared__ short As[128 * 32];   // [m][k], 8KB
    __shared__ short Bs[128 * 32];   // [n][k], 8KB
    const int t = threadIdx.x;
    const int wv = t >> 6, lane = t & 63;
    const int wr = wv >> 1, wc = wv & 1;
    const int m16 = lane & 15, kg = lane >> 4;
    const int row0 = blockIdx.x * 128;
    const int col0 = blockIdx.y * 128;
    const int ldrow = (t >> 2);          // 0..127 (tile row loaded by this thread)
    const int ldk = (t & 3) * 8;         // k-offset within tile
    const int arow = min(row0 + ldrow, NN - 1);
    const short* Ag = (const short*)A + (size_t)arow * 512 + ldk;
    const short* Bg = (const short*)Bt + (size_t)(col0 + ldrow) * 512 + ldk;
    short* AsW = &As[(size_t)(t >> 6) * 512];   // wave base: wv*1024B = wv*512 shorts
    short* BsW = &Bs[(size_t)(t >> 6) * 512];

    floatx4 acc[4][4] = {};
    for (int kb = 0; kb < 512; kb += 32) {
        // stage A,B tiles: 2 rounds each (round p covers bytes p*4096 + wv*1024 + lane*16)
        async_copy16(Ag + kb, AsW);
        async_copy16(Ag + kb + (size_t)64 * 512, AsW + 2048);   // p=1: row +64
        async_copy16(Bg + kb, BsW);
        async_copy16(Bg + kb + (size_t)64 * 512, BsW + 2048);
        __syncthreads();
        short8 a[4], b[4];
        #pragma unroll
        for (int i = 0; i < 4; ++i)
            a[i] = *(const short8*)&As[(wr * 64 + i * 16 + m16) * 32 + kg * 8];
        #pragma unroll
        for (int j = 0; j < 4; ++j)
            b[j] = *(const short8*)&Bs[(wc * 64 + j * 16 + m16) * 32 + kg * 8];
        #pragma unroll
        for (int i = 0; i < 4; ++i)
            #pragma unroll
            for (int j = 0; j < 4; ++j)
                acc[i][j] = __builtin_amdgcn_mfma_f32_16x16x32_bf16(a[i], b[j], acc[i][j], 0, 0, 0);
        __syncthreads();
    }
    // epilogue: relu(acc + bias1) -> bf16 h
    #pragma unroll
    for (int j = 0; j < 4; ++j) {
        int c = col0 + wc * 64 + j * 16 + m16;
        float bj = bias1[c];
        #pragma unroll
        for (int i = 0; i < 4; ++i) {
            int rb = row0 + wr * 64 + i * 16 + kg * 4;
            #pragma unroll
            for (int reg = 0; reg < 4; ++reg) {
                int r = rb + reg;
                if (r < NN)
                    h[(size_t)r * DHID + c] = __float2bfloat16(fmaxf(acc[i][j][reg] + bj, 0.f));
            }
        }
    }
}

// wait: A tile row for p=1 is ldrow+64 -> must clamp too; handled by separate pointer below
// (gemm1m above uses Ag + 64*512 which skips the clamp for p=1; fixed via A2 pointer)

// ---------------- MFMA GEMM 2: h[N][256](bf16) x B2t[512][256] -> out fp32 [N][128] + y bf16 [3][N][128]
__global__ __launch_bounds__(256) void gemm2m(const bf16* __restrict__ A,
        const bf16* __restrict__ Bt, const float* __restrict__ bias2,
        float* __restrict__ out, bf16* __restrict__ y) {
    __shared__ short As[128 * 32];
    __shared__ short Bs[128 * 32];
    const int t = threadIdx.x;
    const int wv = t >> 6, lane = t & 63;
    const int wr = wv >> 1, wc = wv & 1;
    const int m16 = lane & 15, kg = lane >> 4;
    const int row0 = blockIdx.x * 128;
    const int col0 = blockIdx.y * 128;
    const int ldrow = (t >> 2);
    const int ldk = (t & 3) * 8;
    const int arow0 = min(row0 + ldrow, NN - 1);
    const int arow1 = min(row0 + ldrow + 64, NN - 1);
    const short* Ag0 = (const short*)A + (size_t)arow0 * 256 + ldk;
    const short* Ag1 = (const short*)A + (size_t)arow1 * 256 + ldk;
    const short* Bg = (const short*)Bt + (size_t)(col0 + ldrow) * 256 + ldk;
    short* AsW = &As[(size_t)wv * 512];
    short* BsW = &Bs[(size_t)wv * 512];

    floatx4 acc[4][4] = {};
    for (int kb = 0; kb < 256; kb += 32) {
        async_copy16(Ag0 + kb, AsW);
        async_copy16(Ag1 + kb, AsW + 2048);
        async_copy16(Bg + kb, BsW);
        async_copy16(Bg + kb + (size_t)64 * 256, BsW + 2048);
        __syncthreads();
        short8 a[4], b[4];
        #pragma unroll
        for (int i = 0; i < 4; ++i)
            a[i] = *(const short8*)&As[(wr * 64 + i * 16 + m16) * 32 + kg * 8];
        #pragma unroll
        for (int j = 0; j < 4; ++j)
            b[j] = *(const short8*)&Bs[(wc * 64 + j * 16 + m16) * 32 + kg * 8];
        #pragma unroll
        for (int i = 0; i < 4; ++i)
            #pragma unroll
            for (int j = 0; j < 4; ++j)
                acc[i][j] = __builtin_amdgcn_mfma_f32_16x16x32_bf16(a[i], b[j], acc[i][j], 0, 0, 0);
        __syncthreads();
    }
    if (blockIdx.y == 0) {        // self-term + bias -> fp32 out
        #pragma unroll
        for (int j = 0; j < 4; ++j) {
            int c = wc * 64 + j * 16 + m16;   // 0..127
            float bj = bias2[c];
            #pragma unroll
            for (int i = 0; i < 4; ++i) {
                int rb = row0 + wr * 64 + i * 16 + kg * 4;
                #pragma unroll
                for (int reg = 0; reg < 4; ++reg) {
                    int r = rb + reg;
                    if (r < NN) out[(size_t)r * DOUT + c] = acc[i][j][reg] + bj;
                }
            }
        }
    } else {                      // y[rel] -> bf16
        int rel = blockIdx.y - 1;
        bf16* yr = y + (size_t)rel * NN * DOUT;
        #pragma unroll
        for (int j = 0; j < 4; ++j) {
            int c = wc * 64 + j * 16 + m16;
            #pragma unroll
            for (int i = 0; i < 4; ++i) {
                int rb = row0 + wr * 64 + i * 16 + kg * 4;
                #pragma unroll
                for (int reg = 0; reg < 4; ++reg) {
                    int r = rb + reg;
                    if (r < NN) yr[(size_t)r * DOUT + c] = __float2bfloat16(acc[i][j][reg]);
                }
            }
        }
    }
}

// ---------------- gather2: out[n] += sum_r mean_{s in col[r,n]} y[r][s] ----------------
__global__ __launch_bounds__(256) void gather2(const bf16* __restrict__ y,
        const int* __restrict__ rowptr, const int* __restrict__ col,
        float* __restrict__ out) {
    int n = blockIdx.x * 4 + (threadIdx.x >> 6);
    int lane = threadIdx.x & 63;
    float2 acc = *(float2*)&out[(size_t)n * DOUT + lane * 2];
    #pragma unroll
    for (int r = 0; r < RR; ++r) {
        int g = r * NN + n;
        int beg = rowptr[g], end = rowptr[g + 1];
        float a0 = 0.f, a1 = 0.f;
        for (int base = beg; base < end; base += 64) {
            int cnt = min(64, end - base);
            int cidx = (lane < cnt) ? col[base + lane] : 0;
            for (int j = 0; j < cnt; ++j) {
                int s = __shfl(cidx, j, 64);
                bf162 v = *(const bf162*)&y[((size_t)r * NN + s) * DOUT + lane * 2];
                a0 += __bfloat162float(v.x);
                a1 += __bfloat162float(v.y);
            }
        }
        float inv = 1.0f / fmaxf((float)(end - beg), 1.0f);
        acc.x += a0 * inv;
        acc.y += a1 * inv;
    }
    *(float2*)&out[(size_t)n * DOUT + lane * 2] = acc;
}

// ---------------- launch ----------------
extern "C" void kernel_launch(void* const* d_in, const int* in_sizes, int n_in,
                              void* d_out, int out_size, void* d_ws, size_t ws_size,
                              hipStream_t stream) {
    const float* x       = (const float*)d_in[0];
    const int*   src     = (const int*)  d_in[1];
    const int*   dst     = (const int*)  d_in[2];
    const float* Wself1  = (const float*)d_in[3];
    const float* Wneigh1 = (const float*)d_in[4];
    const float* b1      = (const float*)d_in[5];
    const float* Wself2  = (const float*)d_in[6];
    const float* Wneigh2 = (const float*)d_in[7];
    const float* b2      = (const float*)d_in[8];
    float* out = (float*)d_out;

    char* ws = (char*)d_ws;
    // layout:
    //   hist   @0x0000000  cursor @0x00A0000  rowptr @0x0140000  bsums @0x01E0000
    //   bias1  @0x01E1000  bias2  @0x01E2000
    //   col    @0x0200000 (7.2MB)
    //   B1t    @0x0A00000 (256KB bf16)   B2t @0x0A40000 (256KB bf16)
    //   Abig   @0x0B00000 (51.2MB bf16 [N][512]); y overlays Abig (38.4MB, after gemm1)
    //   h      @0x3C00000 (25.6MB bf16 [N][256])  -> ends ~88.5MB
    int*   hist   = (int*)  (ws + 0x0000000ull);
    int*   cursor = (int*)  (ws + 0x00A0000ull);
    int*   rowptr = (int*)  (ws + 0x0140000ull);
    int*   bsums  = (int*)  (ws + 0x01E0000ull);
    float* bias1  = (float*)(ws + 0x01E1000ull);
    float* bias2  = (float*)(ws + 0x01E2000ull);
    int*   col    = (int*)  (ws + 0x0200000ull);
    bf16*  B1t    = (bf16*) (ws + 0x0A00000ull);
    bf16*  B2t    = (bf16*) (ws + 0x0A40000ull);
    bf16*  Abig   = (bf16*) (ws + 0x0B00000ull);
    bf16*  y      = (bf16*) (ws + 0x0B00000ull);   // overlays Abig (dead after gemm1)
    bf16*  h      = (bf16*) (ws + 0x3C00000ull);

    hipMemsetAsync(hist, 0, NRN * sizeof(int), stream);
    hipMemsetAsync(cursor, 0, NRN * sizeof(int), stream);

    build_B1t<<<256 * 512 / 256, 256, 0, stream>>>(Wself1, Wneigh1, B1t);
    build_B2t<<<512 * 256 / 256, 256, 0, stream>>>(Wself2, Wneigh2, B2t);
    build_bias<<<2, 256, 0, stream>>>(b1, b2, bias1, bias2);
    convert_x<<<(NN * 64 + 255) / 256, 256, 0, stream>>>(x, Abig);

    hist_kernel<<<(RR * EE + 255) / 256, 256, 0, stream>>>(dst, hist);
    const int nb = (NRN + 1023) / 1024;
    scan_blocks<<<nb, 256, 0, stream>>>(hist, rowptr, bsums, NRN);
    scan_sums<<<1, 256, 0, stream>>>(bsums, nb);
    add_offsets<<<(NRN + 255) / 256, 256, 0, stream>>>(rowptr, bsums, NRN);
    fill_kernel<<<(RR * EE + 255) / 256, 256, 0, stream>>>(src, dst, rowptr, cursor, col);

    gather1<<<NRN / 4, 256, 0, stream>>>(x, rowptr, col, Abig);

    gemm1m<<<dim3((NN + 127) / 128, 2), 256, 0, stream>>>(Abig, B1t, bias1, h);
    gemm2m<<<dim3((NN + 127) / 128, 4), 256, 0, stream>>>(h, B2t, bias2, out, y);

    gather2<<<NN / 4, 256, 0, stream>>>(y, rowptr, col, out);
}

// Round 5
// 585.694 us; speedup vs baseline: 3.7722x; 1.0293x over previous
//
#include <hip/hip_runtime.h>
#include <hip/hip_bf16.h>
#include <cstddef>

// RSAGEConv: 2-layer hetero SAGE (mean agg), N=50000, R=3, E=600000, 128->256->128.
// fp32 in/out. CSR gather aggregation + bf16 MFMA GEMMs.
// Pipeline:
//  hist -> scan -> fill (CSR)
//  convert_x: Abig[:,0:128] = bf16(x)
//  gather1:   Abig[:,128+128r] = mean_r(bf16 x)   (reads the bf16 copy: half traffic)
//  gemm1m:    h = bf16(relu(Abig @ B1t^T + bias1))   [MFMA, K=512 -> 256]
//  gemm2m:    out(fp32) | y(bf16) = h @ B2t^T + bias2 [MFMA, K=256 -> 512]
//  gather2:   out[n] += sum_r mean_r(y)

#define NN 50000
#define RR 3
#define EE 600000
#define DIN 128
#define DHID 256
#define DOUT 128
#define NRN (RR * NN)

typedef __hip_bfloat16 bf16;
typedef __hip_bfloat162 bf162;
typedef __attribute__((ext_vector_type(8))) short short8;
typedef __attribute__((ext_vector_type(4))) float floatx4;

__device__ __forceinline__ void async_copy16(const void* g, void* l) {
    __builtin_amdgcn_global_load_lds((const __attribute__((address_space(1))) void*)g,
                                     (__attribute__((address_space(3))) void*)l, 16, 0, 0);
}

// ---------------- histogram (indegree) ----------------
__global__ void hist_kernel(const int* __restrict__ dst, int* __restrict__ hist) {
    int idx = blockIdx.x * 256 + threadIdx.x;
    if (idx >= RR * EE) return;
    int r = idx / EE;
    atomicAdd(&hist[r * NN + dst[idx]], 1);
}

// ---------------- exclusive scan over NRN ints ----------------
__global__ __launch_bounds__(256) void scan_blocks(const int* __restrict__ in,
        int* __restrict__ out, int* __restrict__ bsums, int n) {
    int t = threadIdx.x;
    int base = blockIdx.x * 1024 + t * 4;
    int v[4];
    #pragma unroll
    for (int i = 0; i < 4; ++i) v[i] = (base + i < n) ? in[base + i] : 0;
    int s = v[0] + v[1] + v[2] + v[3];
    int lane = t & 63, wid = t >> 6;
    int sc = s;
    #pragma unroll
    for (int d = 1; d < 64; d <<= 1) {
        int tt = __shfl_up(sc, d, 64);
        if (lane >= d) sc += tt;
    }
    __shared__ int wsum[4], woff[4];
    if (lane == 63) wsum[wid] = sc;
    __syncthreads();
    if (t == 0) {
        int a = 0;
        #pragma unroll
        for (int i = 0; i < 4; ++i) { woff[i] = a; a += wsum[i]; }
    }
    __syncthreads();
    int run = sc - s + woff[wid];
    #pragma unroll
    for (int i = 0; i < 4; ++i) {
        if (base + i < n) out[base + i] = run;
        run += v[i];
    }
    if (t == 255) bsums[blockIdx.x] = woff[3] + wsum[3];
}

__global__ __launch_bounds__(256) void scan_sums(int* __restrict__ bsums, int nb) {
    int t = threadIdx.x;
    int v = (t < nb) ? bsums[t] : 0;
    int lane = t & 63, wid = t >> 6;
    int sc = v;
    #pragma unroll
    for (int d = 1; d < 64; d <<= 1) {
        int tt = __shfl_up(sc, d, 64);
        if (lane >= d) sc += tt;
    }
    __shared__ int wsum[4], woff[4];
    if (lane == 63) wsum[wid] = sc;
    __syncthreads();
    if (t == 0) {
        int a = 0;
        #pragma unroll
        for (int i = 0; i < 4; ++i) { woff[i] = a; a += wsum[i]; }
    }
    __syncthreads();
    if (t < nb) bsums[t] = sc - v + woff[wid];
}

__global__ void add_offsets(int* __restrict__ rowptr, const int* __restrict__ bsums,
                            int* __restrict__ cursor, int n) {
    int i = blockIdx.x * 256 + threadIdx.x;
    if (i < n) { rowptr[i] += bsums[i >> 10]; cursor[i] = 0; }
    if (i == 0) rowptr[n] = RR * EE;
}

// ---------------- CSR fill ----------------
__global__ void fill_kernel(const int* __restrict__ src, const int* __restrict__ dst,
                            const int* __restrict__ rowptr, int* __restrict__ cursor,
                            int* __restrict__ col) {
    int idx = blockIdx.x * 256 + threadIdx.x;
    if (idx >= RR * EE) return;
    int r = idx / EE;
    int node = r * NN + dst[idx];
    int pos = rowptr[node] + atomicAdd(&cursor[node], 1);
    col[pos] = src[idx];
}

// ---------------- weight prep (transposed, bf16) ----------------
__global__ void build_B1t(const float* __restrict__ Ws, const float* __restrict__ Wn,
                          bf16* __restrict__ B1t) {
    int idx = blockIdx.x * 256 + threadIdx.x;
    if (idx >= 256 * 512) return;
    int n = idx >> 9, k = idx & 511;
    float v;
    if (k < 128) {
        v = Ws[(size_t)k * 256 + n]
          + Ws[(size_t)(128 + k) * 256 + n]
          + Ws[(size_t)(256 + k) * 256 + n];
    } else {
        int q = k - 128; int r = q >> 7; int kk = q & 127;
        v = Wn[((size_t)r * 128 + kk) * 256 + n];
    }
    B1t[(size_t)n * 512 + k] = __float2bfloat16(v);
}

__global__ void build_B2t(const float* __restrict__ Ws, const float* __restrict__ Wn,
                          bf16* __restrict__ B2t) {
    int idx = blockIdx.x * 256 + threadIdx.x;
    if (idx >= 512 * 256) return;
    int n = idx >> 8, k = idx & 255;
    float v;
    if (n < 128) {
        v = Ws[(size_t)k * 128 + n]
          + Ws[(size_t)(256 + k) * 128 + n]
          + Ws[(size_t)(512 + k) * 128 + n];
    } else {
        int q = n - 128; int r = q >> 7; int nn = q & 127;
        v = Wn[((size_t)r * 256 + k) * 128 + nn];
    }
    B2t[(size_t)n * 256 + k] = __float2bfloat16(v);
}

__global__ void build_bias(const float* __restrict__ b1, const float* __restrict__ b2,
                           float* __restrict__ bias1, float* __restrict__ bias2) {
    int idx = blockIdx.x * 256 + threadIdx.x;
    if (idx < 256) {
        bias1[idx] = b1[idx] + b1[256 + idx] + b1[512 + idx];
    } else if (idx < 384) {
        int j = idx - 256;
        bias2[j] = b2[j] + b2[128 + j] + b2[256 + j];
    }
}

// ---------------- convert x -> Abig cols 0..127 ----------------
__global__ void convert_x(const float* __restrict__ x, bf16* __restrict__ Abig) {
    int idx = blockIdx.x * 256 + threadIdx.x;   // over N*64
    if (idx >= NN * 64) return;
    int n = idx >> 6, c2 = idx & 63;
    float2 v = *(const float2*)&x[(size_t)n * DIN + c2 * 2];
    bf162 o; o.x = __float2bfloat16(v.x); o.y = __float2bfloat16(v.y);
    *(bf162*)&Abig[(size_t)n * 512 + c2 * 2] = o;
}

// ---------------- gather1: Abig[n][128+128r..] = mean_{s in col[r,n]} bf16x[s] ----------------
// Reads the bf16 copy of x living in Abig[:,0:128] (256 B/row, fully coalesced).
__global__ __launch_bounds__(256) void gather1(const int* __restrict__ rowptr,
        const int* __restrict__ col, bf16* __restrict__ Abig) {
    int g = blockIdx.x * 4 + (threadIdx.x >> 6);   // r*NN + n
    int lane = threadIdx.x & 63;
    int r = g / NN;
    int n = g - r * NN;
    int beg = rowptr[g], end = rowptr[g + 1];
    const unsigned* xb = (const unsigned*)Abig;    // row stride 256 uints; lane reads uint (2 bf16)
    float acc0 = 0.f, acc1 = 0.f;
    for (int base = beg; base < end; base += 64) {
        int cnt = min(64, end - base);
        int cidx = (lane < cnt) ? col[base + lane] : 0;
        for (int j = 0; j < cnt; ++j) {
            int s = __shfl(cidx, j, 64);
            unsigned u = xb[(size_t)s * 256 + lane];
            acc0 += __uint_as_float(u << 16);
            acc1 += __uint_as_float(u & 0xffff0000u);
        }
    }
    float inv = 1.0f / fmaxf((float)(end - beg), 1.0f);
    bf162 o;
    o.x = __float2bfloat16(acc0 * inv);
    o.y = __float2bfloat16(acc1 * inv);
    *(bf162*)&Abig[(size_t)n * 512 + 128 + r * 128 + lane * 2] = o;
}

// ---------------- MFMA GEMM 1: Abig[N][512](bf16) x B1t[256][512] -> h bf16 [N][256] ----------------
__global__ __launch_bounds__(256) void gemm1m(const bf16* __restrict__ A,
        const bf16* __restrict__ Bt, const float* __restrict__ bias1,
        bf16* __restrict__ h) {
    __shared__ short As[128 * 32];   // [m][k], 8KB
    __shared__ short Bs[128 * 32];   // [n][k], 8KB
    const int t = threadIdx.x;
    const int wv = t >> 6, lane = t & 63;
    const int wr = wv >> 1, wc = wv & 1;
    const int m16 = lane & 15, kg = lane >> 4;
    const int row0 = blockIdx.x * 128;
    const int col0 = blockIdx.y * 128;
    const int ldrow = (t >> 2);          // 0..63 (64-row half-tile per round)
    const int ldk = (t & 3) * 8;
    const int arow0 = min(row0 + ldrow, NN - 1);
    const int arow1 = min(row0 + ldrow + 64, NN - 1);
    const short* Ag0 = (const short*)A + (size_t)arow0 * 512 + ldk;
    const short* Ag1 = (const short*)A + (size_t)arow1 * 512 + ldk;
    const short* Bg = (const short*)Bt + (size_t)(col0 + ldrow) * 512 + ldk;
    short* AsW = &As[(size_t)wv * 512];
    short* BsW = &Bs[(size_t)wv * 512];

    floatx4 acc[4][4] = {};
    for (int kb = 0; kb < 512; kb += 32) {
        async_copy16(Ag0 + kb, AsW);
        async_copy16(Ag1 + kb, AsW + 2048);
        async_copy16(Bg + kb, BsW);
        async_copy16(Bg + kb + (size_t)64 * 512, BsW + 2048);
        __syncthreads();
        short8 a[4], b[4];
        #pragma unroll
        for (int i = 0; i < 4; ++i)
            a[i] = *(const short8*)&As[(wr * 64 + i * 16 + m16) * 32 + kg * 8];
        #pragma unroll
        for (int j = 0; j < 4; ++j)
            b[j] = *(const short8*)&Bs[(wc * 64 + j * 16 + m16) * 32 + kg * 8];
        #pragma unroll
        for (int i = 0; i < 4; ++i)
            #pragma unroll
            for (int j = 0; j < 4; ++j)
                acc[i][j] = __builtin_amdgcn_mfma_f32_16x16x32_bf16(a[i], b[j], acc[i][j], 0, 0, 0);
        __syncthreads();
    }
    #pragma unroll
    for (int j = 0; j < 4; ++j) {
        int c = col0 + wc * 64 + j * 16 + m16;
        float bj = bias1[c];
        #pragma unroll
        for (int i = 0; i < 4; ++i) {
            int rb = row0 + wr * 64 + i * 16 + kg * 4;
            #pragma unroll
            for (int reg = 0; reg < 4; ++reg) {
                int r = rb + reg;
                if (r < NN)
                    h[(size_t)r * DHID + c] = __float2bfloat16(fmaxf(acc[i][j][reg] + bj, 0.f));
            }
        }
    }
}

// ---------------- MFMA GEMM 2: h[N][256](bf16) x B2t[512][256] -> out fp32 [N][128] + y bf16 [3][N][128]
__global__ __launch_bounds__(256) void gemm2m(const bf16* __restrict__ A,
        const bf16* __restrict__ Bt, const float* __restrict__ bias2,
        float* __restrict__ out, bf16* __restrict__ y) {
    __shared__ short As[128 * 32];
    __shared__ short Bs[128 * 32];
    const int t = threadIdx.x;
    const int wv = t >> 6, lane = t & 63;
    const int wr = wv >> 1, wc = wv & 1;
    const int m16 = lane & 15, kg = lane >> 4;
    const int row0 = blockIdx.x * 128;
    const int col0 = blockIdx.y * 128;
    const int ldrow = (t >> 2);
    const int ldk = (t & 3) * 8;
    const int arow0 = min(row0 + ldrow, NN - 1);
    const int arow1 = min(row0 + ldrow + 64, NN - 1);
    const short* Ag0 = (const short*)A + (size_t)arow0 * 256 + ldk;
    const short* Ag1 = (const short*)A + (size_t)arow1 * 256 + ldk;
    const short* Bg = (const short*)Bt + (size_t)(col0 + ldrow) * 256 + ldk;
    short* AsW = &As[(size_t)wv * 512];
    short* BsW = &Bs[(size_t)wv * 512];

    floatx4 acc[4][4] = {};
    for (int kb = 0; kb < 256; kb += 32) {
        async_copy16(Ag0 + kb, AsW);
        async_copy16(Ag1 + kb, AsW + 2048);
        async_copy16(Bg + kb, BsW);
        async_copy16(Bg + kb + (size_t)64 * 256, BsW + 2048);
        __syncthreads();
        short8 a[4], b[4];
        #pragma unroll
        for (int i = 0; i < 4; ++i)
            a[i] = *(const short8*)&As[(wr * 64 + i * 16 + m16) * 32 + kg * 8];
        #pragma unroll
        for (int j = 0; j < 4; ++j)
            b[j] = *(const short8*)&Bs[(wc * 64 + j * 16 + m16) * 32 + kg * 8];
        #pragma unroll
        for (int i = 0; i < 4; ++i)
            #pragma unroll
            for (int j = 0; j < 4; ++j)
                acc[i][j] = __builtin_amdgcn_mfma_f32_16x16x32_bf16(a[i], b[j], acc[i][j], 0, 0, 0);
        __syncthreads();
    }
    if (blockIdx.y == 0) {        // self-term + bias -> fp32 out
        #pragma unroll
        for (int j = 0; j < 4; ++j) {
            int c = wc * 64 + j * 16 + m16;   // 0..127
            float bj = bias2[c];
            #pragma unroll
            for (int i = 0; i < 4; ++i) {
                int rb = row0 + wr * 64 + i * 16 + kg * 4;
                #pragma unroll
                for (int reg = 0; reg < 4; ++reg) {
                    int r = rb + reg;
                    if (r < NN) out[(size_t)r * DOUT + c] = acc[i][j][reg] + bj;
                }
            }
        }
    } else {                      // y[rel] -> bf16
        int rel = blockIdx.y - 1;
        bf16* yr = y + (size_t)rel * NN * DOUT;
        #pragma unroll
        for (int j = 0; j < 4; ++j) {
            int c = wc * 64 + j * 16 + m16;
            #pragma unroll
            for (int i = 0; i < 4; ++i) {
                int rb = row0 + wr * 64 + i * 16 + kg * 4;
                #pragma unroll
                for (int reg = 0; reg < 4; ++reg) {
                    int r = rb + reg;
                    if (r < NN) yr[(size_t)r * DOUT + c] = __float2bfloat16(acc[i][j][reg]);
                }
            }
        }
    }
}

// ---------------- gather2: out[n] += sum_r mean_{s in col[r,n]} y[r][s] ----------------
__global__ __launch_bounds__(256) void gather2(const bf16* __restrict__ y,
        const int* __restrict__ rowptr, const int* __restrict__ col,
        float* __restrict__ out) {
    int n = blockIdx.x * 4 + (threadIdx.x >> 6);
    int lane = threadIdx.x & 63;
    float2 acc = *(float2*)&out[(size_t)n * DOUT + lane * 2];
    const unsigned* yb = (const unsigned*)y;   // row stride 64 uints
    #pragma unroll
    for (int r = 0; r < RR; ++r) {
        int g = r * NN + n;
        int beg = rowptr[g], end = rowptr[g + 1];
        float a0 = 0.f, a1 = 0.f;
        for (int base = beg; base < end; base += 64) {
            int cnt = min(64, end - base);
            int cidx = (lane < cnt) ? col[base + lane] : 0;
            for (int j = 0; j < cnt; ++j) {
                int s = __shfl(cidx, j, 64);
                unsigned u = yb[((size_t)r * NN + s) * 64 + lane];
                a0 += __uint_as_float(u << 16);
                a1 += __uint_as_float(u & 0xffff0000u);
            }
        }
        float inv = 1.0f / fmaxf((float)(end - beg), 1.0f);
        acc.x += a0 * inv;
        acc.y += a1 * inv;
    }
    *(float2*)&out[(size_t)n * DOUT + lane * 2] = acc;
}

// ---------------- launch ----------------
extern "C" void kernel_launch(void* const* d_in, const int* in_sizes, int n_in,
                              void* d_out, int out_size, void* d_ws, size_t ws_size,
                              hipStream_t stream) {
    const float* x       = (const float*)d_in[0];
    const int*   src     = (const int*)  d_in[1];
    const int*   dst     = (const int*)  d_in[2];
    const float* Wself1  = (const float*)d_in[3];
    const float* Wneigh1 = (const float*)d_in[4];
    const float* b1      = (const float*)d_in[5];
    const float* Wself2  = (const float*)d_in[6];
    const float* Wneigh2 = (const float*)d_in[7];
    const float* b2      = (const float*)d_in[8];
    float* out = (float*)d_out;

    char* ws = (char*)d_ws;
    int*   hist   = (int*)  (ws + 0x0000000ull);
    int*   cursor = (int*)  (ws + 0x00A0000ull);
    int*   rowptr = (int*)  (ws + 0x0140000ull);
    int*   bsums  = (int*)  (ws + 0x01E0000ull);
    float* bias1  = (float*)(ws + 0x01E1000ull);
    float* bias2  = (float*)(ws + 0x01E2000ull);
    int*   col    = (int*)  (ws + 0x0200000ull);
    bf16*  B1t    = (bf16*) (ws + 0x0A00000ull);
    bf16*  B2t    = (bf16*) (ws + 0x0A40000ull);
    bf16*  Abig   = (bf16*) (ws + 0x0B00000ull);   // [N][512] bf16 (51.2MB)
    bf16*  y      = (bf16*) (ws + 0x0B00000ull);   // overlays Abig (dead after gemm1)
    bf16*  h      = (bf16*) (ws + 0x3C00000ull);   // [N][256] bf16 (25.6MB)

    hipMemsetAsync(hist, 0, NRN * sizeof(int), stream);

    build_B1t<<<256 * 512 / 256, 256, 0, stream>>>(Wself1, Wneigh1, B1t);
    build_B2t<<<512 * 256 / 256, 256, 0, stream>>>(Wself2, Wneigh2, B2t);
    build_bias<<<2, 256, 0, stream>>>(b1, b2, bias1, bias2);
    convert_x<<<(NN * 64 + 255) / 256, 256, 0, stream>>>(x, Abig);

    hist_kernel<<<(RR * EE + 255) / 256, 256, 0, stream>>>(dst, hist);
    const int nb = (NRN + 1023) / 1024;
    scan_blocks<<<nb, 256, 0, stream>>>(hist, rowptr, bsums, NRN);
    scan_sums<<<1, 256, 0, stream>>>(bsums, nb);
    add_offsets<<<(NRN + 255) / 256, 256, 0, stream>>>(rowptr, bsums, cursor, NRN);
    fill_kernel<<<(RR * EE + 255) / 256, 256, 0, stream>>>(src, dst, rowptr, cursor, col);

    gather1<<<NRN / 4, 256, 0, stream>>>(rowptr, col, Abig);

    gemm1m<<<dim3((NN + 127) / 128, 2), 256, 0, stream>>>(Abig, B1t, bias1, h);
    gemm2m<<<dim3((NN + 127) / 128, 4), 256, 0, stream>>>(h, B2t, bias2, out, y);

    gather2<<<NN / 4, 256, 0, stream>>>(y, rowptr, col, out);
}

// Round 6
// 487.273 us; speedup vs baseline: 4.5341x; 1.2020x over previous
//
#include <hip/hip_runtime.h>
#include <hip/hip_bf16.h>
#include <cstddef>

// RSAGEConv: 2-layer hetero SAGE (mean agg), N=50000, R=3, E=600000, 128->256->128.
// fp32 in/out. CSR gather aggregation + bf16 MFMA GEMMs.
// Pipeline:
//  hist -> scan -> fill (CSR)
//  convert_x: Abig[:,0:128] = bf16(x)
//  gather1:   Abig[:,128+128r] = mean_r(bf16 x)   (reads the bf16 copy; unroll-4 for MLP)
//  gemm1m:    h = bf16(relu(Abig @ B1t^T + bias1))   [MFMA, K=512 -> 256]
//  gemm2m:    out(fp32) | y(bf16) = h @ B2t^T + bias2 [MFMA, K=256 -> 512]
//  gather2:   out[n] += sum_r mean_r(y)            (unroll-4)

#define NN 50000
#define RR 3
#define EE 600000
#define DIN 128
#define DHID 256
#define DOUT 128
#define NRN (RR * NN)

typedef __hip_bfloat16 bf16;
typedef __hip_bfloat162 bf162;
typedef __attribute__((ext_vector_type(8))) short short8;
typedef __attribute__((ext_vector_type(4))) float floatx4;

__device__ __forceinline__ void async_copy16(const void* g, void* l) {
    __builtin_amdgcn_global_load_lds((const __attribute__((address_space(1))) void*)g,
                                     (__attribute__((address_space(3))) void*)l, 16, 0, 0);
}

// ---------------- histogram (indegree) ----------------
__global__ void hist_kernel(const int* __restrict__ dst, int* __restrict__ hist) {
    int idx = blockIdx.x * 256 + threadIdx.x;
    if (idx >= RR * EE) return;
    int r = idx / EE;
    atomicAdd(&hist[r * NN + dst[idx]], 1);
}

// ---------------- exclusive scan over NRN ints ----------------
__global__ __launch_bounds__(256) void scan_blocks(const int* __restrict__ in,
        int* __restrict__ out, int* __restrict__ bsums, int n) {
    int t = threadIdx.x;
    int base = blockIdx.x * 1024 + t * 4;
    int v[4];
    #pragma unroll
    for (int i = 0; i < 4; ++i) v[i] = (base + i < n) ? in[base + i] : 0;
    int s = v[0] + v[1] + v[2] + v[3];
    int lane = t & 63, wid = t >> 6;
    int sc = s;
    #pragma unroll
    for (int d = 1; d < 64; d <<= 1) {
        int tt = __shfl_up(sc, d, 64);
        if (lane >= d) sc += tt;
    }
    __shared__ int wsum[4], woff[4];
    if (lane == 63) wsum[wid] = sc;
    __syncthreads();
    if (t == 0) {
        int a = 0;
        #pragma unroll
        for (int i = 0; i < 4; ++i) { woff[i] = a; a += wsum[i]; }
    }
    __syncthreads();
    int run = sc - s + woff[wid];
    #pragma unroll
    for (int i = 0; i < 4; ++i) {
        if (base + i < n) out[base + i] = run;
        run += v[i];
    }
    if (t == 255) bsums[blockIdx.x] = woff[3] + wsum[3];
}

__global__ __launch_bounds__(256) void scan_sums(int* __restrict__ bsums, int nb) {
    int t = threadIdx.x;
    int v = (t < nb) ? bsums[t] : 0;
    int lane = t & 63, wid = t >> 6;
    int sc = v;
    #pragma unroll
    for (int d = 1; d < 64; d <<= 1) {
        int tt = __shfl_up(sc, d, 64);
        if (lane >= d) sc += tt;
    }
    __shared__ int wsum[4], woff[4];
    if (lane == 63) wsum[wid] = sc;
    __syncthreads();
    if (t == 0) {
        int a = 0;
        #pragma unroll
        for (int i = 0; i < 4; ++i) { woff[i] = a; a += wsum[i]; }
    }
    __syncthreads();
    if (t < nb) bsums[t] = sc - v + woff[wid];
}

__global__ void add_offsets(int* __restrict__ rowptr, const int* __restrict__ bsums,
                            int* __restrict__ cursor, int n) {
    int i = blockIdx.x * 256 + threadIdx.x;
    if (i < n) { rowptr[i] += bsums[i >> 10]; cursor[i] = 0; }
    if (i == 0) rowptr[n] = RR * EE;
}

// ---------------- CSR fill ----------------
__global__ void fill_kernel(const int* __restrict__ src, const int* __restrict__ dst,
                            const int* __restrict__ rowptr, int* __restrict__ cursor,
                            int* __restrict__ col) {
    int idx = blockIdx.x * 256 + threadIdx.x;
    if (idx >= RR * EE) return;
    int r = idx / EE;
    int node = r * NN + dst[idx];
    int pos = rowptr[node] + atomicAdd(&cursor[node], 1);
    col[pos] = src[idx];
}

// ---------------- weight prep (transposed, bf16) ----------------
__global__ void build_B1t(const float* __restrict__ Ws, const float* __restrict__ Wn,
                          bf16* __restrict__ B1t) {
    int idx = blockIdx.x * 256 + threadIdx.x;
    if (idx >= 256 * 512) return;
    int n = idx >> 9, k = idx & 511;
    float v;
    if (k < 128) {
        v = Ws[(size_t)k * 256 + n]
          + Ws[(size_t)(128 + k) * 256 + n]
          + Ws[(size_t)(256 + k) * 256 + n];
    } else {
        int q = k - 128; int r = q >> 7; int kk = q & 127;
        v = Wn[((size_t)r * 128 + kk) * 256 + n];
    }
    B1t[(size_t)n * 512 + k] = __float2bfloat16(v);
}

__global__ void build_B2t(const float* __restrict__ Ws, const float* __restrict__ Wn,
                          bf16* __restrict__ B2t) {
    int idx = blockIdx.x * 256 + threadIdx.x;
    if (idx >= 512 * 256) return;
    int n = idx >> 8, k = idx & 255;
    float v;
    if (n < 128) {
        v = Ws[(size_t)k * 128 + n]
          + Ws[(size_t)(256 + k) * 128 + n]
          + Ws[(size_t)(512 + k) * 128 + n];
    } else {
        int q = n - 128; int r = q >> 7; int nn = q & 127;
        v = Wn[((size_t)r * 256 + k) * 128 + nn];
    }
    B2t[(size_t)n * 256 + k] = __float2bfloat16(v);
}

__global__ void build_bias(const float* __restrict__ b1, const float* __restrict__ b2,
                           float* __restrict__ bias1, float* __restrict__ bias2) {
    int idx = blockIdx.x * 256 + threadIdx.x;
    if (idx < 256) {
        bias1[idx] = b1[idx] + b1[256 + idx] + b1[512 + idx];
    } else if (idx < 384) {
        int j = idx - 256;
        bias2[j] = b2[j] + b2[128 + j] + b2[256 + j];
    }
}

// ---------------- convert x -> Abig cols 0..127 ----------------
__global__ void convert_x(const float* __restrict__ x, bf16* __restrict__ Abig) {
    int idx = blockIdx.x * 256 + threadIdx.x;   // over N*64
    if (idx >= NN * 64) return;
    int n = idx >> 6, c2 = idx & 63;
    float2 v = *(const float2*)&x[(size_t)n * DIN + c2 * 2];
    bf162 o; o.x = __float2bfloat16(v.x); o.y = __float2bfloat16(v.y);
    *(bf162*)&Abig[(size_t)n * 512 + c2 * 2] = o;
}

__device__ __forceinline__ float bflo(unsigned u) { return __uint_as_float(u << 16); }
__device__ __forceinline__ float bfhi(unsigned u) { return __uint_as_float(u & 0xffff0000u); }

// ---------------- gather1: Abig[n][128+128r..] = mean_{s in col[r,n]} bf16x[s] ----------------
// Unroll-4: 4 independent row-loads in flight per wave (latency hiding).
__global__ __launch_bounds__(256) void gather1(const int* __restrict__ rowptr,
        const int* __restrict__ col, bf16* __restrict__ Abig) {
    int g = blockIdx.x * 4 + (threadIdx.x >> 6);   // r*NN + n
    int lane = threadIdx.x & 63;
    int r = g / NN;
    int n = g - r * NN;
    int beg = rowptr[g], end = rowptr[g + 1];
    const unsigned* xb = (const unsigned*)Abig;    // row stride 256 uints
    float acc0 = 0.f, acc1 = 0.f;
    for (int base = beg; base < end; base += 64) {
        int cnt = min(64, end - base);
        int cidx = (lane < cnt) ? col[base + lane] : 0;
        int j = 0;
        for (; j + 4 <= cnt; j += 4) {
            int s0 = __shfl(cidx, j,     64);
            int s1 = __shfl(cidx, j + 1, 64);
            int s2 = __shfl(cidx, j + 2, 64);
            int s3 = __shfl(cidx, j + 3, 64);
            unsigned u0 = xb[(size_t)s0 * 256 + lane];
            unsigned u1 = xb[(size_t)s1 * 256 + lane];
            unsigned u2 = xb[(size_t)s2 * 256 + lane];
            unsigned u3 = xb[(size_t)s3 * 256 + lane];
            acc0 += bflo(u0) + bflo(u1) + bflo(u2) + bflo(u3);
            acc1 += bfhi(u0) + bfhi(u1) + bfhi(u2) + bfhi(u3);
        }
        for (; j < cnt; ++j) {
            int s = __shfl(cidx, j, 64);
            unsigned u = xb[(size_t)s * 256 + lane];
            acc0 += bflo(u);
            acc1 += bfhi(u);
        }
    }
    float inv = 1.0f / fmaxf((float)(end - beg), 1.0f);
    bf162 o;
    o.x = __float2bfloat16(acc0 * inv);
    o.y = __float2bfloat16(acc1 * inv);
    *(bf162*)&Abig[(size_t)n * 512 + 128 + r * 128 + lane * 2] = o;
}

// ---------------- MFMA GEMM 1: Abig[N][512](bf16) x B1t[256][512] -> h bf16 [N][256] ----------------
__global__ __launch_bounds__(256) void gemm1m(const bf16* __restrict__ A,
        const bf16* __restrict__ Bt, const float* __restrict__ bias1,
        bf16* __restrict__ h) {
    __shared__ short As[128 * 32];   // [m][k], 8KB
    __shared__ short Bs[128 * 32];   // [n][k], 8KB
    const int t = threadIdx.x;
    const int wv = t >> 6, lane = t & 63;
    const int wr = wv >> 1, wc = wv & 1;
    const int m16 = lane & 15, kg = lane >> 4;
    const int row0 = blockIdx.x * 128;
    const int col0 = blockIdx.y * 128;
    const int ldrow = (t >> 2);
    const int ldk = (t & 3) * 8;
    const int arow0 = min(row0 + ldrow, NN - 1);
    const int arow1 = min(row0 + ldrow + 64, NN - 1);
    const short* Ag0 = (const short*)A + (size_t)arow0 * 512 + ldk;
    const short* Ag1 = (const short*)A + (size_t)arow1 * 512 + ldk;
    const short* Bg = (const short*)Bt + (size_t)(col0 + ldrow) * 512 + ldk;
    short* AsW = &As[(size_t)wv * 512];
    short* BsW = &Bs[(size_t)wv * 512];

    floatx4 acc[4][4] = {};
    for (int kb = 0; kb < 512; kb += 32) {
        async_copy16(Ag0 + kb, AsW);
        async_copy16(Ag1 + kb, AsW + 2048);
        async_copy16(Bg + kb, BsW);
        async_copy16(Bg + kb + (size_t)64 * 512, BsW + 2048);
        __syncthreads();
        short8 a[4], b[4];
        #pragma unroll
        for (int i = 0; i < 4; ++i)
            a[i] = *(const short8*)&As[(wr * 64 + i * 16 + m16) * 32 + kg * 8];
        #pragma unroll
        for (int j = 0; j < 4; ++j)
            b[j] = *(const short8*)&Bs[(wc * 64 + j * 16 + m16) * 32 + kg * 8];
        #pragma unroll
        for (int i = 0; i < 4; ++i)
            #pragma unroll
            for (int j = 0; j < 4; ++j)
                acc[i][j] = __builtin_amdgcn_mfma_f32_16x16x32_bf16(a[i], b[j], acc[i][j], 0, 0, 0);
        __syncthreads();
    }
    #pragma unroll
    for (int j = 0; j < 4; ++j) {
        int c = col0 + wc * 64 + j * 16 + m16;
        float bj = bias1[c];
        #pragma unroll
        for (int i = 0; i < 4; ++i) {
            int rb = row0 + wr * 64 + i * 16 + kg * 4;
            #pragma unroll
            for (int reg = 0; reg < 4; ++reg) {
                int r = rb + reg;
                if (r < NN)
                    h[(size_t)r * DHID + c] = __float2bfloat16(fmaxf(acc[i][j][reg] + bj, 0.f));
            }
        }
    }
}

// ---------------- MFMA GEMM 2: h[N][256](bf16) x B2t[512][256] -> out fp32 [N][128] + y bf16 [3][N][128]
__global__ __launch_bounds__(256) void gemm2m(const bf16* __restrict__ A,
        const bf16* __restrict__ Bt, const float* __restrict__ bias2,
        float* __restrict__ out, bf16* __restrict__ y) {
    __shared__ short As[128 * 32];
    __shared__ short Bs[128 * 32];
    const int t = threadIdx.x;
    const int wv = t >> 6, lane = t & 63;
    const int wr = wv >> 1, wc = wv & 1;
    const int m16 = lane & 15, kg = lane >> 4;
    const int row0 = blockIdx.x * 128;
    const int col0 = blockIdx.y * 128;
    const int ldrow = (t >> 2);
    const int ldk = (t & 3) * 8;
    const int arow0 = min(row0 + ldrow, NN - 1);
    const int arow1 = min(row0 + ldrow + 64, NN - 1);
    const short* Ag0 = (const short*)A + (size_t)arow0 * 256 + ldk;
    const short* Ag1 = (const short*)A + (size_t)arow1 * 256 + ldk;
    const short* Bg = (const short*)Bt + (size_t)(col0 + ldrow) * 256 + ldk;
    short* AsW = &As[(size_t)wv * 512];
    short* BsW = &Bs[(size_t)wv * 512];

    floatx4 acc[4][4] = {};
    for (int kb = 0; kb < 256; kb += 32) {
        async_copy16(Ag0 + kb, AsW);
        async_copy16(Ag1 + kb, AsW + 2048);
        async_copy16(Bg + kb, BsW);
        async_copy16(Bg + kb + (size_t)64 * 256, BsW + 2048);
        __syncthreads();
        short8 a[4], b[4];
        #pragma unroll
        for (int i = 0; i < 4; ++i)
            a[i] = *(const short8*)&As[(wr * 64 + i * 16 + m16) * 32 + kg * 8];
        #pragma unroll
        for (int j = 0; j < 4; ++j)
            b[j] = *(const short8*)&Bs[(wc * 64 + j * 16 + m16) * 32 + kg * 8];
        #pragma unroll
        for (int i = 0; i < 4; ++i)
            #pragma unroll
            for (int j = 0; j < 4; ++j)
                acc[i][j] = __builtin_amdgcn_mfma_f32_16x16x32_bf16(a[i], b[j], acc[i][j], 0, 0, 0);
        __syncthreads();
    }
    if (blockIdx.y == 0) {        // self-term + bias -> fp32 out
        #pragma unroll
        for (int j = 0; j < 4; ++j) {
            int c = wc * 64 + j * 16 + m16;   // 0..127
            float bj = bias2[c];
            #pragma unroll
            for (int i = 0; i < 4; ++i) {
                int rb = row0 + wr * 64 + i * 16 + kg * 4;
                #pragma unroll
                for (int reg = 0; reg < 4; ++reg) {
                    int r = rb + reg;
                    if (r < NN) out[(size_t)r * DOUT + c] = acc[i][j][reg] + bj;
                }
            }
        }
    } else {                      // y[rel] -> bf16
        int rel = blockIdx.y - 1;
        bf16* yr = y + (size_t)rel * NN * DOUT;
        #pragma unroll
        for (int j = 0; j < 4; ++j) {
            int c = wc * 64 + j * 16 + m16;
            #pragma unroll
            for (int i = 0; i < 4; ++i) {
                int rb = row0 + wr * 64 + i * 16 + kg * 4;
                #pragma unroll
                for (int reg = 0; reg < 4; ++reg) {
                    int r = rb + reg;
                    if (r < NN) yr[(size_t)r * DOUT + c] = __float2bfloat16(acc[i][j][reg]);
                }
            }
        }
    }
}

// ---------------- gather2: out[n] += sum_r mean_{s in col[r,n]} y[r][s] (unroll-4) ----------------
__global__ __launch_bounds__(256) void gather2(const bf16* __restrict__ y,
        const int* __restrict__ rowptr, const int* __restrict__ col,
        float* __restrict__ out) {
    int n = blockIdx.x * 4 + (threadIdx.x >> 6);
    int lane = threadIdx.x & 63;
    float2 acc = *(float2*)&out[(size_t)n * DOUT + lane * 2];
    const unsigned* yb = (const unsigned*)y;   // row stride 64 uints
    #pragma unroll
    for (int r = 0; r < RR; ++r) {
        const unsigned* ybr = yb + (size_t)r * NN * 64;
        int g = r * NN + n;
        int beg = rowptr[g], end = rowptr[g + 1];
        float a0 = 0.f, a1 = 0.f;
        for (int base = beg; base < end; base += 64) {
            int cnt = min(64, end - base);
            int cidx = (lane < cnt) ? col[base + lane] : 0;
            int j = 0;
            for (; j + 4 <= cnt; j += 4) {
                int s0 = __shfl(cidx, j,     64);
                int s1 = __shfl(cidx, j + 1, 64);
                int s2 = __shfl(cidx, j + 2, 64);
                int s3 = __shfl(cidx, j + 3, 64);
                unsigned u0 = ybr[(size_t)s0 * 64 + lane];
                unsigned u1 = ybr[(size_t)s1 * 64 + lane];
                unsigned u2 = ybr[(size_t)s2 * 64 + lane];
                unsigned u3 = ybr[(size_t)s3 * 64 + lane];
                a0 += bflo(u0) + bflo(u1) + bflo(u2) + bflo(u3);
                a1 += bfhi(u0) + bfhi(u1) + bfhi(u2) + bfhi(u3);
            }
            for (; j < cnt; ++j) {
                int s = __shfl(cidx, j, 64);
                unsigned u = ybr[(size_t)s * 64 + lane];
                a0 += bflo(u);
                a1 += bfhi(u);
            }
        }
        float inv = 1.0f / fmaxf((float)(end - beg), 1.0f);
        acc.x += a0 * inv;
        acc.y += a1 * inv;
    }
    *(float2*)&out[(size_t)n * DOUT + lane * 2] = acc;
}

// ---------------- launch ----------------
extern "C" void kernel_launch(void* const* d_in, const int* in_sizes, int n_in,
                              void* d_out, int out_size, void* d_ws, size_t ws_size,
                              hipStream_t stream) {
    const float* x       = (const float*)d_in[0];
    const int*   src     = (const int*)  d_in[1];
    const int*   dst     = (const int*)  d_in[2];
    const float* Wself1  = (const float*)d_in[3];
    const float* Wneigh1 = (const float*)d_in[4];
    const float* b1      = (const float*)d_in[5];
    const float* Wself2  = (const float*)d_in[6];
    const float* Wneigh2 = (const float*)d_in[7];
    const float* b2      = (const float*)d_in[8];
    float* out = (float*)d_out;

    char* ws = (char*)d_ws;
    int*   hist   = (int*)  (ws + 0x0000000ull);
    int*   cursor = (int*)  (ws + 0x00A0000ull);
    int*   rowptr = (int*)  (ws + 0x0140000ull);
    int*   bsums  = (int*)  (ws + 0x01E0000ull);
    float* bias1  = (float*)(ws + 0x01E1000ull);
    float* bias2  = (float*)(ws + 0x01E2000ull);
    int*   col    = (int*)  (ws + 0x0200000ull);
    bf16*  B1t    = (bf16*) (ws + 0x0A00000ull);
    bf16*  B2t    = (bf16*) (ws + 0x0A40000ull);
    bf16*  Abig   = (bf16*) (ws + 0x0B00000ull);   // [N][512] bf16 (51.2MB)
    bf16*  y      = (bf16*) (ws + 0x0B00000ull);   // overlays Abig (dead after gemm1)
    bf16*  h      = (bf16*) (ws + 0x3C00000ull);   // [N][256] bf16 (25.6MB)

    hipMemsetAsync(hist, 0, NRN * sizeof(int), stream);

    build_B1t<<<256 * 512 / 256, 256, 0, stream>>>(Wself1, Wneigh1, B1t);
    build_B2t<<<512 * 256 / 256, 256, 0, stream>>>(Wself2, Wneigh2, B2t);
    build_bias<<<2, 256, 0, stream>>>(b1, b2, bias1, bias2);
    convert_x<<<(NN * 64 + 255) / 256, 256, 0, stream>>>(x, Abig);

    hist_kernel<<<(RR * EE + 255) / 256, 256, 0, stream>>>(dst, hist);
    const int nb = (NRN + 1023) / 1024;
    scan_blocks<<<nb, 256, 0, stream>>>(hist, rowptr, bsums, NRN);
    scan_sums<<<1, 256, 0, stream>>>(bsums, nb);
    add_offsets<<<(NRN + 255) / 256, 256, 0, stream>>>(rowptr, bsums, cursor, NRN);
    fill_kernel<<<(RR * EE + 255) / 256, 256, 0, stream>>>(src, dst, rowptr, cursor, col);

    gather1<<<NRN / 4, 256, 0, stream>>>(rowptr, col, Abig);

    gemm1m<<<dim3((NN + 127) / 128, 2), 256, 0, stream>>>(Abig, B1t, bias1, h);
    gemm2m<<<dim3((NN + 127) / 128, 4), 256, 0, stream>>>(h, B2t, bias2, out, y);

    gather2<<<NN / 4, 256, 0, stream>>>(y, rowptr, col, out);
}